// Round 3
// baseline (889.249 us; speedup 1.0000x reference)
//
#include <hip/hip_runtime.h>
#include <hip/hip_bf16.h>
#include <stdint.h>

// GATv2Conv(1028->256, heads=1, self-loops) on gfx950.
// R3: inputs/outputs are FP32 (threshold = 2% of max|ref| proved the fp32 path;
// prior bf16 reinterpretation of fp32 bytes was the NaN source).
// Pipeline: fp32->bf16 convert (x, W^T) -> bf16 MFMA GEMM (xl|xr, fp32 acc,
// bf16 xf) -> CSR build -> fused per-dst online-softmax gather (1 wave/node).

#define N_NODES 50000
#define N_EDGES 1600000
#define D_IN    1028
#define KPAD    1056   // D_IN padded to x32; xb/Wt zero-filled beyond 1028
#define D_OUT   256
#define NB      512    // xf row: cols [0,256)=xl, [256,512)=xr

typedef __bf16 bf16x8 __attribute__((ext_vector_type(8)));
typedef float  f32x4  __attribute__((ext_vector_type(4)));

static __device__ __forceinline__ void gl_lds16(const void* g, void* l) {
  __builtin_amdgcn_global_load_lds(
      (const __attribute__((address_space(1))) unsigned int*)g,
      (__attribute__((address_space(3))) unsigned int*)l, 16, 0, 0);
}
static __device__ __forceinline__ float bf2f(unsigned short u) {
  union { unsigned int i; float f; } c; c.i = ((unsigned int)u) << 16; return c.f;
}
static __device__ __forceinline__ unsigned short f2bf(float f) {
  union { float f; unsigned int i; } c; c.f = f;
  unsigned int r = 0x7fffu + ((c.i >> 16) & 1u);  // round-to-nearest-even
  return (unsigned short)((c.i + r) >> 16);
}

// ---------------- edge_index dtype autodetect --------------------------------
// Values < 50000: if data is int64, high word of every entry is 0.
// mode==0 -> int64, mode!=0 -> int32.
__global__ void k_mode(const unsigned int* __restrict__ ei32, int* __restrict__ mode) {
  int t = blockIdx.x * 256 + threadIdx.x;  // 2048 probes
  if (t < 2048 && ei32[2 * t + 1] != 0u) atomicOr(mode, 1);
}

// ---------------- x fp32 -> xb bf16 [N][KPAD], zero-padded -------------------
__global__ void k_x2b(const float* __restrict__ x, unsigned short* __restrict__ xb) {
  long long idx = (long long)blockIdx.x * 256 + threadIdx.x;
  if (idx >= (long long)N_NODES * KPAD) return;
  int n = (int)(idx / KPAD);
  int k = (int)(idx - (long long)n * KPAD);
  xb[idx] = (k < D_IN) ? f2bf(x[(size_t)n * D_IN + k]) : (unsigned short)0;
}

// ---------------- Wt[n][k] = W[k][n] (bf16), zero-padded ---------------------
__global__ void k_wt(const float* __restrict__ Wl, const float* __restrict__ Wr,
                     unsigned short* __restrict__ Wt) {
  int idx = blockIdx.x * 256 + threadIdx.x;
  if (idx >= NB * KPAD) return;
  int k = idx / NB;        // 0..1055
  int n = idx - k * NB;    // 0..511 (consecutive threads -> coalesced W reads)
  unsigned short v = 0;
  if (k < D_IN) v = f2bf((n < D_OUT) ? Wl[k * D_OUT + n] : Wr[k * D_OUT + (n - D_OUT)]);
  Wt[(size_t)n * KPAD + k] = v;
}

// ---------------- GEMM: xf[M][512] = xb[M][.] @ Wt^T (bf16 MFMA, bf16 out) ---
// 128x128 tile, BK=32, 16x16x32 mfma, 4 waves each 64x64.
__global__ __launch_bounds__(256) void k_gemm(const unsigned short* __restrict__ xb,
                                              const unsigned short* __restrict__ Wt,
                                              unsigned short* __restrict__ xf, int M) {
  __shared__ unsigned short As[128 * 32];  // [m][k], 32 bf16 (64B) per row
  __shared__ unsigned short Bs[128 * 32];  // [n][k]
  const int tid = threadIdx.x;
  const int w = tid >> 6, lane = tid & 63;
  const int m0 = blockIdx.x * 128, n0 = blockIdx.y * 128;
  const int wm = (w >> 1) * 64, wn = (w & 1) * 64;

  f32x4 zero = {0.f, 0.f, 0.f, 0.f};
  f32x4 acc[4][4];
#pragma unroll
  for (int i = 0; i < 4; ++i)
#pragma unroll
    for (int j = 0; j < 4; ++j) acc[i][j] = zero;

  const int lrow = lane >> 2, lch = lane & 3;  // 16 rows x 4 x16B chunks / call

  for (int k0 = 0; k0 < KPAD; k0 += 32) {
    __syncthreads();
    // A staging: wave w stages rows [w*32, w*32+32); xb rows are KPAD long,
    // 16B-aligned, zero-padded -> no tail hazards.
#pragma unroll
    for (int j = 0; j < 2; ++j) {
      int gm = m0 + w * 32 + j * 16 + lrow;
      if (gm >= M) gm = M - 1;
      const char* g = (const char*)xb + ((size_t)gm * KPAD + k0) * 2 + lch * 16;
      gl_lds16(g, &As[(w * 32 + j * 16) * 32]);
    }
#pragma unroll
    for (int j = 0; j < 2; ++j) {
      int gn = n0 + w * 32 + j * 16 + lrow;
      const char* g = (const char*)Wt + ((size_t)gn * KPAD + k0) * 2 + lch * 16;
      gl_lds16(g, &Bs[(w * 32 + j * 16) * 32]);
    }
    __syncthreads();

    bf16x8 af[4], bfr[4];
#pragma unroll
    for (int t = 0; t < 4; ++t)
      af[t] = *(const bf16x8*)&As[(wm + t * 16 + (lane & 15)) * 32 + (lane >> 4) * 8];
#pragma unroll
    for (int t = 0; t < 4; ++t)
      bfr[t] = *(const bf16x8*)&Bs[(wn + t * 16 + (lane & 15)) * 32 + (lane >> 4) * 8];
#pragma unroll
    for (int mt = 0; mt < 4; ++mt)
#pragma unroll
      for (int nt = 0; nt < 4; ++nt)
        acc[mt][nt] = __builtin_amdgcn_mfma_f32_16x16x32_bf16(af[mt], bfr[nt], acc[mt][nt], 0, 0, 0);
  }

  // C/D layout: col = lane&15, row = (lane>>4)*4 + r
  const int col = lane & 15, rq = (lane >> 4) * 4;
#pragma unroll
  for (int mt = 0; mt < 4; ++mt)
#pragma unroll
    for (int nt = 0; nt < 4; ++nt)
#pragma unroll
      for (int r = 0; r < 4; ++r) {
        int m = m0 + wm + mt * 16 + rq + r;
        if (m < M) xf[(size_t)m * NB + (n0 + wn + nt * 16 + col)] = f2bf(acc[mt][nt][r]);
      }
}

// ---------------- CSR build --------------------------------------------------
static __device__ __forceinline__ int load_idx(const int* ei, const long long* ei64,
                                               int md, int pos, int n) {
  int v = md ? ei[pos] : (int)ei64[pos];
  v = v < 0 ? 0 : (v >= n ? n - 1 : v);  // defense: never OOB downstream
  return v;
}

__global__ void k_hist(const int* __restrict__ ei, const int* __restrict__ mode,
                       int E, int* __restrict__ deg, int n) {
  int e = blockIdx.x * blockDim.x + threadIdx.x;
  if (e < E) {
    int d = load_idx(ei, (const long long*)ei, *mode, E + e, n);
    atomicAdd(&deg[d], 1);
  }
}

__global__ void k_scan(const int* __restrict__ deg, int* __restrict__ rowstart,
                       int* __restrict__ cursor, int n) {
  __shared__ int wsum[16];
  __shared__ int woff[16];
  __shared__ int running_sh;
  if (threadIdx.x == 0) running_sh = 0;
  __syncthreads();
  for (int start = 0; start < n; start += 1024) {
    int i = start + (int)threadIdx.x;
    int v = (i < n) ? deg[i] : 0;
    int x = v;
#pragma unroll
    for (int off = 1; off < 64; off <<= 1) {
      int y = __shfl_up(x, off, 64);
      if ((int)(threadIdx.x & 63) >= off) x += y;
    }
    if ((threadIdx.x & 63) == 63) wsum[threadIdx.x >> 6] = x;
    __syncthreads();
    if (threadIdx.x == 0) {
      int a = running_sh;
      for (int wv = 0; wv < 16; ++wv) { woff[wv] = a; a += wsum[wv]; }
      running_sh = a;
    }
    __syncthreads();
    int excl = woff[threadIdx.x >> 6] + (x - v);
    if (i < n) { rowstart[i] = excl; cursor[i] = excl; }
    __syncthreads();
  }
  if (threadIdx.x == 0) rowstart[n] = running_sh;
}

__global__ void k_scatter(const int* __restrict__ ei, const int* __restrict__ mode,
                          int E, int* __restrict__ cursor, int* __restrict__ ssrc, int n) {
  int e = blockIdx.x * blockDim.x + threadIdx.x;
  if (e < E) {
    int md = *mode;
    int s = load_idx(ei, (const long long*)ei, md, e, n);
    int d = load_idx(ei, (const long long*)ei, md, E + e, n);
    int pos = atomicAdd(&cursor[d], 1);
    if (pos >= 0 && pos < E) ssrc[pos] = s;
  }
}

// ---------------- fused gather + online softmax + aggregate ------------------
static __device__ __forceinline__ float4 load_bf4(const unsigned short* p) {
  ushort4 u = *(const ushort4*)p;
  float4 f; f.x = bf2f(u.x); f.y = bf2f(u.y); f.z = bf2f(u.z); f.w = bf2f(u.w);
  return f;
}
static __device__ __forceinline__ float edge_e(float4 v, float4 xr, float4 a) {
  float t0 = v.x + xr.x; t0 = t0 > 0.f ? t0 : 0.2f * t0;
  float t1 = v.y + xr.y; t1 = t1 > 0.f ? t1 : 0.2f * t1;
  float t2 = v.z + xr.z; t2 = t2 > 0.f ? t2 : 0.2f * t2;
  float t3 = v.w + xr.w; t3 = t3 > 0.f ? t3 : 0.2f * t3;
  float p = fmaf(a.x, t0, fmaf(a.y, t1, fmaf(a.z, t2, a.w * t3)));
#pragma unroll
  for (int off = 32; off > 0; off >>= 1) p += __shfl_xor(p, off, 64);
  return p;
}

__global__ __launch_bounds__(256) void k_gat(const unsigned short* __restrict__ xf,
    const int* __restrict__ rowstart, const int* __restrict__ ssrc,
    const float* __restrict__ att, const float* __restrict__ bias,
    float* __restrict__ out, int n) {
  const int gw = (int)((blockIdx.x * blockDim.x + threadIdx.x) >> 6);  // 1 wave/dst
  const int lane = (int)(threadIdx.x & 63);
  if (gw >= n) return;

  // row = 512 bf16; lane covers cols [4*lane, 4*lane+4) of xl and of xr
  const float4 a = ((const float4*)att)[lane];
  float4 xr = load_bf4(xf + (size_t)gw * NB + D_OUT + 4 * lane);

  // self-loop first (guarantees nonempty segment)
  float4 xl = load_bf4(xf + (size_t)gw * NB + 4 * lane);
  float m = edge_e(xl, xr, a);
  float l = 1.f;
  float4 acc = xl;

  const int beg = rowstart[gw], end = rowstart[gw + 1];
  for (int i = beg; i < end; ++i) {
    int s = ssrc[i];
    s = s < 0 ? 0 : (s >= n ? n - 1 : s);
    float4 v = load_bf4(xf + (size_t)s * NB + 4 * lane);
    float e = edge_e(v, xr, a);
    float mn = fmaxf(m, e);
    float sc = __expf(m - mn);
    float p  = __expf(e - mn);
    acc.x = acc.x * sc + p * v.x;
    acc.y = acc.y * sc + p * v.y;
    acc.z = acc.z * sc + p * v.z;
    acc.w = acc.w * sc + p * v.w;
    l = l * sc + p;
    m = mn;
  }

  float inv = 1.f / l;
  const float4 b = ((const float4*)bias)[lane];
  float4 o;
  o.x = fmaf(acc.x, inv, b.x);
  o.y = fmaf(acc.y, inv, b.y);
  o.z = fmaf(acc.z, inv, b.z);
  o.w = fmaf(acc.w, inv, b.w);
  ((float4*)out)[(size_t)gw * 64 + lane] = o;
}

// ---------------- launch -----------------------------------------------------
extern "C" void kernel_launch(void* const* d_in, const int* in_sizes, int n_in,
                              void* d_out, int out_size, void* d_ws, size_t ws_size,
                              hipStream_t stream) {
  (void)in_sizes; (void)n_in; (void)out_size; (void)ws_size;
  const float* x   = (const float*)d_in[0];
  const int*   ei  = (const int*)d_in[1];
  const float* Wl  = (const float*)d_in[2];
  const float* Wr  = (const float*)d_in[3];
  const float* att = (const float*)d_in[4];
  const float* bia = (const float*)d_in[5];
  float* out = (float*)d_out;

  const int N = N_NODES;
  const int E = N_EDGES;

  char* ws = (char*)d_ws;
  size_t off = 0;
  unsigned short* xb = (unsigned short*)(ws + off); off += (size_t)N * KPAD * 2;  // 105.6 MB
  unsigned short* xf = (unsigned short*)(ws + off); off += (size_t)N * NB * 2;    //  51.2 MB
  unsigned short* Wt = (unsigned short*)(ws + off); off += (size_t)NB * KPAD * 2; //   1.1 MB
  off = (off + 255) & ~(size_t)255;
  int* deg      = (int*)(ws + off); off += (size_t)N * 4;
  int* rowstart = (int*)(ws + off); off += (size_t)(N + 1) * 4;
  off = (off + 255) & ~(size_t)255;
  int* cursor   = (int*)(ws + off); off += (size_t)N * 4;
  int* ssrc     = (int*)(ws + off); off += (size_t)E * 4;
  off = (off + 255) & ~(size_t)255;
  int* mode     = (int*)(ws + off); off += 256;     // total ~165 MB

  hipMemsetAsync(deg, 0, (size_t)N * 4, stream);
  hipMemsetAsync(mode, 0, 4, stream);
  k_mode<<<8, 256, 0, stream>>>((const unsigned int*)ei, mode);
  {
    long long tot = (long long)N * KPAD;
    k_x2b<<<(unsigned)((tot + 255) / 256), 256, 0, stream>>>(x, xb);
  }
  k_wt<<<(NB * KPAD + 255) / 256, 256, 0, stream>>>(Wl, Wr, Wt);
  k_gemm<<<dim3((N + 127) / 128, NB / 128), 256, 0, stream>>>(xb, Wt, xf, N);
  k_hist<<<(E + 255) / 256, 256, 0, stream>>>(ei, mode, E, deg, N);
  k_scan<<<1, 1024, 0, stream>>>(deg, rowstart, cursor, N);
  k_scatter<<<(E + 255) / 256, 256, 0, stream>>>(ei, mode, E, cursor, ssrc, N);
  k_gat<<<(N + 3) / 4, 256, 0, stream>>>(xf, rowstart, ssrc, att, bia, out, N);
}